// Round 24
// baseline (255.961 us; speedup 1.0000x reference)
//
#include <hip/hip_runtime.h>
#include <stdint.h>
#include <stddef.h>

// ---------- types ----------
typedef _Float16 half_t;
typedef half_t half8  __attribute__((ext_vector_type(8)));
typedef half_t half4v __attribute__((ext_vector_type(4)));
typedef float  f32x4  __attribute__((ext_vector_type(4)));

__device__ __forceinline__ float fast_sigmoid(float x) {
    float e = __builtin_amdgcn_exp2f(-1.44269504f * x);
    return __builtin_amdgcn_rcpf(1.0f + e);
}
__device__ __forceinline__ float fast_tanh(float x) {
    float e = __builtin_amdgcn_exp2f(2.88539008f * x);
    return 1.0f - 2.0f * __builtin_amdgcn_rcpf(1.0f + e);
}

// ---------------------------------------------------------------------------
// Prep: W [1024][256] f32 row-major -> wave-window-contiguous MFMA-B order,
// pass-grouped: per (w,kt) the 8 fragments are [f0,f1,o0,o1 | i0,i1,g0,g1]
// (pass A = first 2 KB half, pass B = second). Element addr:
//   (((w*8 + kt)*8 + v)*64 + l)*8 + e,
//   v: gate f->0+j, o->2+j, i->4+j, g->6+j  (tile T = gate*16 + w*2 + j).
// Value: B[k = kt*32 + (l>>4)*8 + e, col = T*16 + (l&15)] -- same bijection
// as the LDS A-fragments (validated R1-R23, absmax 2e-3).
// ---------------------------------------------------------------------------
__global__ __launch_bounds__(64) void shuffle_w_kernel(
    const float* __restrict__ W, half_t* __restrict__ out)
{
    const int blk = blockIdx.x;         // 512 = 64 T * 8 kt
    const int T = blk >> 3, kt = blk & 7;
    const int l = threadIdx.x;
    const int w = (T & 15) >> 1, j = T & 1, g = T >> 4;
    const int v = (g == 1) ? j : (g == 3) ? 2 + j : (g == 0) ? 4 + j : 6 + j;
    const int col = T * 16 + (l & 15);
    const int k0 = kt * 32 + ((l >> 4) << 3);
    half8 vv;
#pragma unroll
    for (int e = 0; e < 8; ++e) vv[e] = (half_t)W[col * 256 + k0 + e];
    *reinterpret_cast<half8*>(
        out + ((size_t)((w * 8 + kt) * 8 + v) * 64 + l) * 8) = vv;
}

// ---------------------------------------------------------------------------
// 2-gate (4 N-tile) GEMM half-pass, b ping-pong window dbuf, kt RUNTIME
// (unroll 1) -- used for pass A (head cowork doesn't index arrays by wi)
// and phase 0. acc[mt*4+n] += hx @ frag(off + n).
// ---------------------------------------------------------------------------
template <typename CW>
__device__ __forceinline__ void gemm_halfA(
    f32x4* acc, const half_t* __restrict__ lhx,
    const half_t* Ws, int w, int off, int lm, int lg, int l, CW&& cw)
{
    asm volatile("" : "+v"(Ws));   // anti-LICM
    const half_t* wb = Ws + (size_t)w * 32768 + off + l * 8;
    half8 bA[4], bB[4];
#pragma unroll
    for (int v = 0; v < 4; ++v)
        bA[v] = *reinterpret_cast<const half8*>(wb + v * 512);
#pragma unroll 1
    for (int kt2 = 0; kt2 < 4; ++kt2) {
        const int kt = kt2 * 2;
#pragma unroll
        for (int v = 0; v < 4; ++v)
            bB[v] = *reinterpret_cast<const half8*>(wb + (kt + 1) * 4096 + v * 512);
        {
            half8 a[4];
#pragma unroll
            for (int mt = 0; mt < 4; ++mt) {
                const int p = mt * 16 + lm;
                const int k = (kt * 32 + lg * 8) ^ ((p & 7) << 4);
                a[mt] = *reinterpret_cast<const half8*>(&lhx[p * 256 + k]);
            }
#pragma unroll
            for (int v = 0; v < 4; ++v)
#pragma unroll
                for (int mt = 0; mt < 4; ++mt)
                    acc[mt * 4 + v] = __builtin_amdgcn_mfma_f32_16x16x32_f16(
                        a[mt], bA[v], acc[mt * 4 + v], 0, 0, 0);
        }
        cw(kt);
        __builtin_amdgcn_sched_barrier(0);
#pragma unroll
        for (int v = 0; v < 4; ++v)
            bA[v] = *reinterpret_cast<const half8*>(wb + ((kt + 2) & 7) * 4096 + v * 512);
        {
            half8 a[4];
#pragma unroll
            for (int mt = 0; mt < 4; ++mt) {
                const int p = mt * 16 + lm;
                const int k = ((kt + 1) * 32 + lg * 8) ^ ((p & 7) << 4);
                a[mt] = *reinterpret_cast<const half8*>(&lhx[p * 256 + k]);
            }
#pragma unroll
            for (int v = 0; v < 4; ++v)
#pragma unroll
                for (int mt = 0; mt < 4; ++mt)
                    acc[mt * 4 + v] = __builtin_amdgcn_mfma_f32_16x16x32_f16(
                        a[mt], bB[v], acc[mt * 4 + v], 0, 0, 0);
        }
        cw(kt + 1);
        __builtin_amdgcn_sched_barrier(0);
    }
}

// ---------------------------------------------------------------------------
// Same shape, kt FULLY UNROLLED (fences kept): cowork wi constant-folds so
// epiA may index acc/cxr/og arrays (rule #20). Used for pass B.
// ---------------------------------------------------------------------------
template <typename CW>
__device__ __forceinline__ void gemm_halfB(
    f32x4* acc, const half_t* __restrict__ lhx,
    const half_t* Ws, int w, int off, int lm, int lg, int l, CW&& cw)
{
    asm volatile("" : "+v"(Ws));   // anti-LICM
    const half_t* wb = Ws + (size_t)w * 32768 + off + l * 8;
    half8 bA[4], bB[4];
#pragma unroll
    for (int v = 0; v < 4; ++v)
        bA[v] = *reinterpret_cast<const half8*>(wb + v * 512);
#pragma unroll
    for (int kt2 = 0; kt2 < 4; ++kt2) {
        const int kt = kt2 * 2;
#pragma unroll
        for (int v = 0; v < 4; ++v)
            bB[v] = *reinterpret_cast<const half8*>(wb + (kt + 1) * 4096 + v * 512);
        {
            half8 a[4];
#pragma unroll
            for (int mt = 0; mt < 4; ++mt) {
                const int p = mt * 16 + lm;
                const int k = (kt * 32 + lg * 8) ^ ((p & 7) << 4);
                a[mt] = *reinterpret_cast<const half8*>(&lhx[p * 256 + k]);
            }
#pragma unroll
            for (int v = 0; v < 4; ++v)
#pragma unroll
                for (int mt = 0; mt < 4; ++mt)
                    acc[mt * 4 + v] = __builtin_amdgcn_mfma_f32_16x16x32_f16(
                        a[mt], bA[v], acc[mt * 4 + v], 0, 0, 0);
        }
        cw(kt);
        __builtin_amdgcn_sched_barrier(0);
#pragma unroll
        for (int v = 0; v < 4; ++v)
            bA[v] = *reinterpret_cast<const half8*>(wb + ((kt + 2) & 7) * 4096 + v * 512);
        {
            half8 a[4];
#pragma unroll
            for (int mt = 0; mt < 4; ++mt) {
                const int p = mt * 16 + lm;
                const int k = ((kt + 1) * 32 + lg * 8) ^ ((p & 7) << 4);
                a[mt] = *reinterpret_cast<const half8*>(&lhx[p * 256 + k]);
            }
#pragma unroll
            for (int v = 0; v < 4; ++v)
#pragma unroll
                for (int mt = 0; mt < 4; ++mt)
                    acc[mt * 4 + v] = __builtin_amdgcn_mfma_f32_16x16x32_f16(
                        a[mt], bB[v], acc[mt * 4 + v], 0, 0, 0);
        }
        cw(kt + 1);
        __builtin_amdgcn_sched_barrier(0);
    }
}

// ---------------------------------------------------------------------------
// Persistent LSTM: block = 64 rows x 16 steps, 8 waves (512 threads),
// 1 blk/CU, 2 waves/SIMD. R22/R23 base (223 us, zero spills) + R24:
// 2-pass gates with accA HELD IN ITS AGPR HALF through pass B, and epiA
// (cxr *= sig(f); og = sig(o) f16 -- 128 trans-instr) run as pass-B cowork
// in the MFMA shadow. Exposed epilogue trans drops ~40%. R15's spill causes
// removed: full-unroll pass B keeps fences; head cowork only in pass A;
// no a-dbuf. Ledgers: pass A ~102, pass B ~112 arch (<=128).
// LDS: hx 32 KB (XOR-swizzled) + xp 128 KB = 160 KB.
// ---------------------------------------------------------------------------
__global__ __launch_bounds__(512)
void lstm_kernel(
    const float* __restrict__ x,      // [8][256][1600]
    const float* __restrict__ hx0,    // [12800][256]
    const float* __restrict__ cx0,    // [12800][256]
    const float* __restrict__ b_ih,   // [1024]
    const float* __restrict__ b_hh,   // [1024]
    const float* __restrict__ W_lin,  // [2][256]
    const float* __restrict__ b_lin,  // [2]
    const half_t* __restrict__ Wih_s, // shuffled f16
    const half_t* __restrict__ Whh_s, // shuffled f16
    float* __restrict__ out)          // [12800][16][2]
{
    __shared__ __align__(16) half_t lds_hx[64 * 256];        // 32 KB
    __shared__ __align__(16) half_t lds_xp[8 * 32 * 64 * 4]; // 128 KB

    const int tid = threadIdx.x;
    const int w  = tid >> 6;   // wave 0..7 owns h-cols [w*32, w*32+32)
    const int l  = tid & 63;
    const int lm = l & 15;
    const int lg = l >> 4;
    const int w2 = w * 2;

    const int row0 = blockIdx.x * 64;     // 200 blocks * 64 rows
    const int bb_  = row0 / 1600;
    const int p0   = row0 % 1600;

    // ---- stage x tile into lds_hx, f16 swizzled (coalesced on p) ----
    {
        const float* xin = x + (size_t)bb_ * 409600 + p0;   // x[b][c][p0+p]
        for (int it = 0; it < 32; ++it) {
            int idx = it * 512 + tid;
            int p = idx & 63, c = idx >> 6;
            lds_hx[p * 256 + (c ^ ((p & 7) << 4))] = (half_t)xin[c * 1600 + p];
        }
    }
    __syncthreads();

    f32x4 accA[16], accB[16];
    auto nocw = [](int) {};

    // ---- phase 0: x_proj = x @ W_ih^T + b_ih + b_hh, 2 half-passes ----
    // pass A tiles: f(16+w2+n), o(48+w2+n-2); pass B: i(w2+n), g(32+w2+n-2)
#pragma unroll 1
    for (int pass = 0; pass < 2; ++pass) {
#pragma unroll
        for (int n = 0; n < 4; ++n) {
            int T = (pass == 0)
                ? ((n < 2) ? 16 + w2 + n : 48 + w2 + (n - 2))
                : ((n < 2) ? w2 + n      : 32 + w2 + (n - 2));
            float bias = b_ih[T * 16 + lm] + b_hh[T * 16 + lm];
#pragma unroll
            for (int mt = 0; mt < 4; ++mt)
                accA[mt * 4 + n] = (f32x4){bias, bias, bias, bias};
        }
        gemm_halfA(accA, lds_hx, Wih_s, w, pass * 2048, lm, lg, l, nocw);
#pragma unroll
        for (int f = 0; f < 16; ++f) {
            half4v xv;
#pragma unroll
            for (int r = 0; r < 4; ++r) xv[r] = (half_t)accA[f][r];
            *reinterpret_cast<half4v*>(
                &lds_xp[((w * 32 + pass * 16 + f) * 64 + l) * 4]) = xv;
        }
    }
    __syncthreads();   // x tile fully consumed, xp written

    // ---- stage h0 into lds_hx (coalesced on c); cx into registers ----
    {
        const float* hin = hx0 + (size_t)row0 * 256;
        for (int it = 0; it < 32; ++it) {
            int idx = it * 512 + tid;
            int c = idx & 255, p = idx >> 8;
            lds_hx[p * 256 + (c ^ ((p & 7) << 4))] = (half_t)hin[p * 256 + c];
        }
    }
    float cxr[32];
#pragma unroll
    for (int mt = 0; mt < 4; ++mt)
#pragma unroll
        for (int j = 0; j < 2; ++j)
#pragma unroll
            for (int r = 0; r < 4; ++r) {
                int p = mt * 16 + lg * 4 + r;
                int c = w * 32 + j * 16 + lm;
                cxr[(mt * 2 + j) * 4 + r] = cx0[(size_t)(row0 + p) * 256 + c];
            }
    const float blin0 = b_lin[0], blin1 = b_lin[1];
    const int ph = tid >> 3;          // head: row 0..63
    const int ho = (tid >> 2) & 1;    // head: output 0..1
    const int hq = tid & 3;           // head: quarter of 256 h-cols
    __syncthreads();

    // ---------------- 16 recurrent steps ----------------
#pragma unroll 1
    for (int t = 0; t < 16; ++t) {
        half4v og[8];   // sig(o), f16 (filled by epiA cowork in pass B)

        // head(t-1): 8 windows x 2 cb; W_lin float4 pipelined (R16-proven)
        const float* wl = W_lin + ho * 256 + hq * 64;
        asm volatile("" : "+v"(wl));
        float hs = 0.0f;
        float4 hwv0, hwv1;
        if (t > 0) {
            hwv0 = *reinterpret_cast<const float4*>(wl + 0);
            hwv1 = *reinterpret_cast<const float4*>(wl + 4);
        }
        auto head_cw = [&](int wi) {
            if (t > 0) {
#pragma unroll
                for (int ii = 0; ii < 2; ++ii) {
                    int cb = wi * 2 + ii;
                    int c0 = hq * 64 + cb * 4;
                    half4v u = *reinterpret_cast<const half4v*>(
                        &lds_hx[ph * 256 + (c0 ^ ((ph & 7) << 4))]);
                    float4 wv = ii ? hwv1 : hwv0;
                    if (cb + 2 < 16) {
                        float4 nx = *reinterpret_cast<const float4*>(
                            wl + (cb + 2) * 4);
                        if (ii) hwv1 = nx; else hwv0 = nx;
                    }
                    float h0 = (float)u[0], h1 = (float)u[1];
                    float h2 = (float)u[2], h3 = (float)u[3];
                    hs += fmaxf(h0, 0.01f * h0) * wv.x;
                    hs += fmaxf(h1, 0.01f * h1) * wv.y;
                    hs += fmaxf(h2, 0.01f * h2) * wv.z;
                    hs += fmaxf(h3, 0.01f * h3) * wv.w;
                }
            }
        };

        // accA init = xp slots 0..15 (chunked, R14/R18-proven)
#pragma unroll
        for (int fc = 0; fc < 16; fc += 4) {
#pragma unroll
            for (int f = fc; f < fc + 4; ++f) {
                half4v u = *reinterpret_cast<const half4v*>(
                    &lds_xp[((w * 32 + f) * 64 + l) * 4]);
#pragma unroll
                for (int r = 0; r < 4; ++r) accA[f][r] = (float)u[r];
            }
            __builtin_amdgcn_sched_barrier(0);
        }

        // ---- pass A: gates (f,o); head(t-1) in the MFMA shadow ----
        gemm_halfA(accA, lds_hx, Whh_s, w, 0, lm, lg, l, head_cw);
        if (t > 0) {
            hs += __shfl_xor(hs, 1);
            hs += __shfl_xor(hs, 2);
            if (hq == 0)
                out[((size_t)(row0 + ph) * 16 + (t - 1)) * 2 + ho] =
                    hs + (ho ? blin1 : blin0);
        }

        // accB init = xp slots 16..31 (chunked)
#pragma unroll
        for (int fc = 0; fc < 16; fc += 4) {
#pragma unroll
            for (int f = fc; f < fc + 4; ++f) {
                half4v u = *reinterpret_cast<const half4v*>(
                    &lds_xp[((w * 32 + 16 + f) * 64 + l) * 4]);
#pragma unroll
                for (int r = 0; r < 4; ++r) accB[f][r] = (float)u[r];
            }
            __builtin_amdgcn_sched_barrier(0);
        }

        // epiA as pass-B cowork: window wi handles cells v = wi*4..wi*4+3
        // (mt = wi>>1, j = wi&1, r = 0..3) -- all indices constant-fold
        // under gemm_halfB's full unroll.
        auto epiA_cw = [&](int wi) {
            const int mt = wi >> 1, j = wi & 1;
#pragma unroll
            for (int r = 0; r < 4; ++r) {
                float fv = accA[mt * 4 + 0 + j][r];
                float ov = accA[mt * 4 + 2 + j][r];
                cxr[(mt * 2 + j) * 4 + r] *= fast_sigmoid(fv);
                og[mt * 2 + j][r] = (half_t)fast_sigmoid(ov);
            }
        };

        // ---- pass B: gates (i,g); epiA in the MFMA shadow ----
        gemm_halfB(accB, lds_hx, Whh_s, w, 2048, lm, lg, l, epiA_cw);

        __syncthreads();   // all waves finished reading lds_hx(t)

        // epiB: finish cell update; write hx(t+1) (f16, swizzled)
#pragma unroll
        for (int mt = 0; mt < 4; ++mt)
#pragma unroll
            for (int j = 0; j < 2; ++j)
#pragma unroll
                for (int r = 0; r < 4; ++r) {
                    const int ci = (mt * 2 + j) * 4 + r;
                    float iv = accB[mt * 4 + 0 + j][r];
                    float gv = accB[mt * 4 + 2 + j][r];
                    float cxn = cxr[ci] + fast_sigmoid(iv) * fast_tanh(gv);
                    cxr[ci] = cxn;
                    float h = (float)og[mt * 2 + j][r] * fast_tanh(cxn);
                    int p  = mt * 16 + lg * 4 + r;
                    int cc = w * 32 + j * 16 + lm;
                    lds_hx[p * 256 + (cc ^ ((p & 7) << 4))] = (half_t)h;
                }
        __syncthreads();   // hx(t+1) visible to all (next pass A + head)
    }

    // ---- final head (t = 15) ----
    {
        const float* wl = W_lin + ho * 256 + hq * 64;
        asm volatile("" : "+v"(wl));
        float s = 0.0f;
#pragma unroll 2
        for (int cb = 0; cb < 16; ++cb) {
            int c0 = hq * 64 + cb * 4;
            half4v u = *reinterpret_cast<const half4v*>(
                &lds_hx[ph * 256 + (c0 ^ ((ph & 7) << 4))]);
            float4 wv = *reinterpret_cast<const float4*>(wl + cb * 4);
            float h0 = (float)u[0], h1 = (float)u[1];
            float h2 = (float)u[2], h3 = (float)u[3];
            s += fmaxf(h0, 0.01f * h0) * wv.x;
            s += fmaxf(h1, 0.01f * h1) * wv.y;
            s += fmaxf(h2, 0.01f * h2) * wv.z;
            s += fmaxf(h3, 0.01f * h3) * wv.w;
        }
        s += __shfl_xor(s, 1);
        s += __shfl_xor(s, 2);
        if (hq == 0)
            out[((size_t)(row0 + ph) * 16 + 15) * 2 + ho] =
                s + (ho ? blin1 : blin0);
    }
}

// ---------------------------------------------------------------------------
extern "C" void kernel_launch(void* const* d_in, const int* in_sizes, int n_in,
                              void* d_out, int out_size, void* d_ws, size_t ws_size,
                              hipStream_t stream)
{
    const float* x    = (const float*)d_in[0];
    const float* hx   = (const float*)d_in[1];
    const float* cx   = (const float*)d_in[2];
    const float* Wih  = (const float*)d_in[3];
    const float* Whh  = (const float*)d_in[4];
    const float* bih  = (const float*)d_in[5];
    const float* bhh  = (const float*)d_in[6];
    const float* Wlin = (const float*)d_in[7];
    const float* blin = (const float*)d_in[8];
    float* out = (float*)d_out;

    half_t* wih_s = (half_t*)d_ws;             // 512 KB
    half_t* whh_s = wih_s + 1024 * 256;        // 512 KB

    shuffle_w_kernel<<<512, 64, 0, stream>>>(Wih, wih_s);
    shuffle_w_kernel<<<512, 64, 0, stream>>>(Whh, whh_s);
    lstm_kernel<<<200, 512, 0, stream>>>(x, hx, cx, bih, bhh, Wlin, blin,
                                         wih_s, whh_s, out);
}

// Round 25
// 250.127 us; speedup vs baseline: 1.0233x; 1.0233x over previous
//
#include <hip/hip_runtime.h>
#include <stdint.h>
#include <stddef.h>

// ---------- types ----------
typedef _Float16 half_t;
typedef half_t half8  __attribute__((ext_vector_type(8)));
typedef half_t half4v __attribute__((ext_vector_type(4)));
typedef float  f32x4  __attribute__((ext_vector_type(4)));

__device__ __forceinline__ float fast_sigmoid(float x) {
    float e = __builtin_amdgcn_exp2f(-1.44269504f * x);
    return __builtin_amdgcn_rcpf(1.0f + e);
}
__device__ __forceinline__ float fast_tanh(float x) {
    float e = __builtin_amdgcn_exp2f(2.88539008f * x);
    return 1.0f - 2.0f * __builtin_amdgcn_rcpf(1.0f + e);
}

// ---------------------------------------------------------------------------
// Prep: W [1024][256] f32 row-major -> wave-window-contiguous MFMA-B order.
// Tile T = g*16 + w*2 + j; slot v = g*2 + j. Element addr:
// (((w*8 + kt)*8 + v)*64 + l)*8 + e  -- window kt's 8 fragments for wave w
// are one contiguous 8 KB run (two 4 KB halves: v 0..3, v 4..7).
// Value: B[k = kt*32 + (l>>4)*8 + e, col = T*16 + (l&15)] -- same bijection
// as the LDS A-fragments (validated R1-R24, absmax 2e-3).
// ---------------------------------------------------------------------------
__global__ __launch_bounds__(64) void shuffle_w_kernel(
    const float* __restrict__ W, half_t* __restrict__ out)
{
    const int blk = blockIdx.x;         // 512 = 64 T * 8 kt
    const int T = blk >> 3, kt = blk & 7;
    const int l = threadIdx.x;
    const int w = (T & 15) >> 1, j = T & 1, g = T >> 4;
    const int v = g * 2 + j;
    const int col = T * 16 + (l & 15);
    const int k0 = kt * 32 + ((l >> 4) << 3);
    half8 vv;
#pragma unroll
    for (int e = 0; e < 8; ++e) vv[e] = (half_t)W[col * 256 + k0 + e];
    *reinterpret_cast<half8*>(
        out + ((size_t)((w * 8 + kt) * 8 + v) * 64 + l) * 8) = vv;
}

// ---------------------------------------------------------------------------
// SINGLE-PASS 4-gate GEMM, half-window B dbuf + A kt-dbuf (R23, 223 us)
// + R25: s_setprio(1) around each MFMA cluster (T5) -- zero register cost;
// boosts the MFMA-issuing wave's arbitration vs the SIMD-sharing wave's
// loads/VALU when the two waves drift out of phase.
// ---------------------------------------------------------------------------
template <typename CoWork>
__device__ __forceinline__ void gemm_all(
    f32x4* acc, const half_t* __restrict__ lhx,
    const half_t* Ws, int w, int lm, int lg, int l, CoWork&& cowork)
{
    asm volatile("" : "+v"(Ws));   // anti-LICM: recompute bases per call
    const half_t* wb = Ws + (size_t)w * 32768 + l * 8;
    half8 bA[4], bB[4];
    half8 aP[2][4];                // ping-pong A fragments, indexed by kt&1
#pragma unroll
    for (int v = 0; v < 4; ++v)
        bA[v] = *reinterpret_cast<const half8*>(wb + v * 512);
#pragma unroll
    for (int mt = 0; mt < 4; ++mt) {
        const int p = mt * 16 + lm;
        const int k = (lg * 8) ^ ((p & 7) << 4);
        aP[0][mt] = *reinterpret_cast<const half8*>(&lhx[p * 256 + k]);
    }

#pragma unroll 2
    for (int kt = 0; kt < 8; ++kt) {
        const half_t* q  = wb + kt * 4096;
        const half_t* qn = wb + ((kt + 1) & 7) * 4096;
        // half 0: prefetch this kt's v=4..7 into bB; MFMA v=0..3 with bA
#pragma unroll
        for (int v = 0; v < 4; ++v)
            bB[v] = *reinterpret_cast<const half8*>(q + 2048 + v * 512);
        __builtin_amdgcn_s_setprio(1);
#pragma unroll
        for (int v = 0; v < 4; ++v)
#pragma unroll
            for (int mt = 0; mt < 4; ++mt)
                acc[mt * 8 + v] = __builtin_amdgcn_mfma_f32_16x16x32_f16(
                    aP[kt & 1][mt], bA[v], acc[mt * 8 + v], 0, 0, 0);
        __builtin_amdgcn_s_setprio(0);
        cowork(kt * 2);
        __builtin_amdgcn_sched_barrier(0);
        // half 1: prefetch next kt's v=0..3 into bA and next kt's a into
        // aP[(kt+1)&1] (kt=7 wraps -- value unused, harmless);
        // MFMA v=4..7 with bB
#pragma unroll
        for (int v = 0; v < 4; ++v)
            bA[v] = *reinterpret_cast<const half8*>(qn + v * 512);
#pragma unroll
        for (int mt = 0; mt < 4; ++mt) {
            const int p = mt * 16 + lm;
            const int k = ((((kt + 1) & 7) * 32) + lg * 8) ^ ((p & 7) << 4);
            aP[(kt + 1) & 1][mt] =
                *reinterpret_cast<const half8*>(&lhx[p * 256 + k]);
        }
        __builtin_amdgcn_s_setprio(1);
#pragma unroll
        for (int v = 0; v < 4; ++v)
#pragma unroll
            for (int mt = 0; mt < 4; ++mt)
                acc[mt * 8 + 4 + v] = __builtin_amdgcn_mfma_f32_16x16x32_f16(
                    aP[kt & 1][mt], bB[v], acc[mt * 8 + 4 + v], 0, 0, 0);
        __builtin_amdgcn_s_setprio(0);
        cowork(kt * 2 + 1);
        __builtin_amdgcn_sched_barrier(0);
    }
}

// ---------------------------------------------------------------------------
// Persistent LSTM: block = 64 rows x 16 steps, 8 waves (512 threads),
// 1 blk/CU, 2 waves/SIMD. R23 base (223 us, zero spills; R24's epiA-cowork
// re-spilled and is reverted) + setprio on MFMA clusters.
// Ledger (gemm): cxr 32 + b 32 + a 32 + head 8 + addr ~15 = ~119 <= 128.
// LDS: hx 32 KB (XOR-swizzled) + xp 128 KB = 160 KB.
// ---------------------------------------------------------------------------
__global__ __launch_bounds__(512)
void lstm_kernel(
    const float* __restrict__ x,      // [8][256][1600]
    const float* __restrict__ hx0,    // [12800][256]
    const float* __restrict__ cx0,    // [12800][256]
    const float* __restrict__ b_ih,   // [1024]
    const float* __restrict__ b_hh,   // [1024]
    const float* __restrict__ W_lin,  // [2][256]
    const float* __restrict__ b_lin,  // [2]
    const half_t* __restrict__ Wih_s, // shuffled f16
    const half_t* __restrict__ Whh_s, // shuffled f16
    float* __restrict__ out)          // [12800][16][2]
{
    __shared__ __align__(16) half_t lds_hx[64 * 256];        // 32 KB
    __shared__ __align__(16) half_t lds_xp[8 * 32 * 64 * 4]; // 128 KB

    const int tid = threadIdx.x;
    const int w  = tid >> 6;   // wave 0..7 owns h-cols [w*32, w*32+32)
    const int l  = tid & 63;
    const int lm = l & 15;
    const int lg = l >> 4;
    const int w2 = w * 2;

    const int row0 = blockIdx.x * 64;     // 200 blocks * 64 rows
    const int bb_  = row0 / 1600;
    const int p0   = row0 % 1600;

    // ---- stage x tile into lds_hx, f16 swizzled (coalesced on p) ----
    {
        const float* xin = x + (size_t)bb_ * 409600 + p0;   // x[b][c][p0+p]
        for (int it = 0; it < 32; ++it) {
            int idx = it * 512 + tid;
            int p = idx & 63, c = idx >> 6;
            lds_hx[p * 256 + (c ^ ((p & 7) << 4))] = (half_t)xin[c * 1600 + p];
        }
    }
    __syncthreads();

    f32x4 acc[32];
    auto nocw = [](int) {};

    // ---------------- phase 0: x_proj = x @ W_ih^T + b_ih + b_hh ----------
#pragma unroll
    for (int g = 0; g < 4; ++g)
#pragma unroll
        for (int j = 0; j < 2; ++j) {
            int col = (g * 16 + w2 + j) * 16 + lm;
            float bias = b_ih[col] + b_hh[col];
#pragma unroll
            for (int mt = 0; mt < 4; ++mt)
                acc[mt * 8 + g * 2 + j] = (f32x4){bias, bias, bias, bias};
        }
    gemm_all(acc, lds_hx, Wih_s, w, lm, lg, l, nocw);

    // dump x_proj to own-wave LDS region as f16 (read back identically)
#pragma unroll
    for (int f = 0; f < 32; ++f) {
        half4v xv;
#pragma unroll
        for (int r = 0; r < 4; ++r) xv[r] = (half_t)acc[f][r];
        *reinterpret_cast<half4v*>(&lds_xp[((w * 32 + f) * 64 + l) * 4]) = xv;
    }
    __syncthreads();   // x tile fully consumed, xp written

    // ---- stage h0 into lds_hx (coalesced on c); cx into registers ----
    {
        const float* hin = hx0 + (size_t)row0 * 256;
        for (int it = 0; it < 32; ++it) {
            int idx = it * 512 + tid;
            int c = idx & 255, p = idx >> 8;
            lds_hx[p * 256 + (c ^ ((p & 7) << 4))] = (half_t)hin[p * 256 + c];
        }
    }
    float cxr[32];
#pragma unroll
    for (int mt = 0; mt < 4; ++mt)
#pragma unroll
        for (int j = 0; j < 2; ++j)
#pragma unroll
            for (int r = 0; r < 4; ++r) {
                int p = mt * 16 + lg * 4 + r;
                int c = w * 32 + j * 16 + lm;
                cxr[(mt * 2 + j) * 4 + r] = cx0[(size_t)(row0 + p) * 256 + c];
            }
    const float blin0 = b_lin[0], blin1 = b_lin[1];
    const int ph = tid >> 3;          // head: row 0..63
    const int ho = (tid >> 2) & 1;    // head: output 0..1
    const int hq = tid & 3;           // head: quarter of 256 h-cols
    __syncthreads();

    // ---------------- 16 recurrent steps ----------------
#pragma unroll 1
    for (int t = 0; t < 16; ++t) {
        // head(t-1): one cb per half-window (16 total); W_lin float4
        // pipelined one half-window ahead (8-reg state)
        const float* wl = W_lin + ho * 256 + hq * 64;
        asm volatile("" : "+v"(wl));
        float hs = 0.0f;
        float4 hwv;
        if (t > 0) hwv = *reinterpret_cast<const float4*>(wl);
        auto head_cw = [&](int wi) {
            if (t > 0) {
                int c0 = hq * 64 + wi * 4;
                half4v u = *reinterpret_cast<const half4v*>(
                    &lds_hx[ph * 256 + (c0 ^ ((ph & 7) << 4))]);
                float4 wv = hwv;
                if (wi < 15)
                    hwv = *reinterpret_cast<const float4*>(wl + (wi + 1) * 4);
                float h0 = (float)u[0], h1 = (float)u[1];
                float h2 = (float)u[2], h3 = (float)u[3];
                hs += fmaxf(h0, 0.01f * h0) * wv.x;
                hs += fmaxf(h1, 0.01f * h1) * wv.y;
                hs += fmaxf(h2, 0.01f * h2) * wv.z;
                hs += fmaxf(h3, 0.01f * h3) * wv.w;
            }
        };

        // acc init = x_proj, software-pipelined chunks (loads of chunk c+1
        // issue before chunk c's cvts; full unroll -> static indices)
        {
            half4v ib[2][4];
#pragma unroll
            for (int f = 0; f < 4; ++f)
                ib[0][f] = *reinterpret_cast<const half4v*>(
                    &lds_xp[((w * 32 + f) * 64 + l) * 4]);
#pragma unroll
            for (int c = 0; c < 8; ++c) {
                if (c < 7) {
#pragma unroll
                    for (int f = 0; f < 4; ++f)
                        ib[(c + 1) & 1][f] = *reinterpret_cast<const half4v*>(
                            &lds_xp[((w * 32 + (c + 1) * 4 + f) * 64 + l) * 4]);
                }
#pragma unroll
                for (int f = 0; f < 4; ++f)
#pragma unroll
                    for (int r = 0; r < 4; ++r)
                        acc[c * 4 + f][r] = (float)ib[c & 1][f][r];
                __builtin_amdgcn_sched_barrier(0);
            }
        }

        // single GEMM pass: all 4 gates; head(t-1) in the MFMA shadow
        gemm_all(acc, lds_hx, Whh_s, w, lm, lg, l, head_cw);
        if (t > 0) {
            hs += __shfl_xor(hs, 1);
            hs += __shfl_xor(hs, 2);
            if (hq == 0)
                out[((size_t)(row0 + ph) * 16 + (t - 1)) * 2 + ho] =
                    hs + (ho ? blin1 : blin0);
        }

        __syncthreads();   // all waves finished reading lds_hx(t)

        // epilogue: full cell update (all 4 gates local); write hx(t+1)
#pragma unroll
        for (int mt = 0; mt < 4; ++mt)
#pragma unroll
            for (int j = 0; j < 2; ++j)
#pragma unroll
                for (int r = 0; r < 4; ++r) {
                    const int ci = (mt * 2 + j) * 4 + r;
                    float iv = acc[mt * 8 + 0 + j][r];
                    float fv = acc[mt * 8 + 2 + j][r];
                    float gv = acc[mt * 8 + 4 + j][r];
                    float ov = acc[mt * 8 + 6 + j][r];
                    float cxn = fast_sigmoid(fv) * cxr[ci] +
                                fast_sigmoid(iv) * fast_tanh(gv);
                    cxr[ci] = cxn;
                    float h = fast_sigmoid(ov) * fast_tanh(cxn);
                    int p  = mt * 16 + lg * 4 + r;
                    int cc = w * 32 + j * 16 + lm;
                    lds_hx[p * 256 + (cc ^ ((p & 7) << 4))] = (half_t)h;
                }
        __syncthreads();   // hx(t+1) visible to all (next gemm + head)
    }

    // ---- final head (t = 15) ----
    {
        const float* wl = W_lin + ho * 256 + hq * 64;
        asm volatile("" : "+v"(wl));
        float s = 0.0f;
#pragma unroll 2
        for (int cb = 0; cb < 16; ++cb) {
            int c0 = hq * 64 + cb * 4;
            half4v u = *reinterpret_cast<const half4v*>(
                &lds_hx[ph * 256 + (c0 ^ ((ph & 7) << 4))]);
            float4 wv = *reinterpret_cast<const float4*>(wl + cb * 4);
            float h0 = (float)u[0], h1 = (float)u[1];
            float h2 = (float)u[2], h3 = (float)u[3];
            s += fmaxf(h0, 0.01f * h0) * wv.x;
            s += fmaxf(h1, 0.01f * h1) * wv.y;
            s += fmaxf(h2, 0.01f * h2) * wv.z;
            s += fmaxf(h3, 0.01f * h3) * wv.w;
        }
        s += __shfl_xor(s, 1);
        s += __shfl_xor(s, 2);
        if (hq == 0)
            out[((size_t)(row0 + ph) * 16 + 15) * 2 + ho] =
                s + (ho ? blin1 : blin0);
    }
}

// ---------------------------------------------------------------------------
extern "C" void kernel_launch(void* const* d_in, const int* in_sizes, int n_in,
                              void* d_out, int out_size, void* d_ws, size_t ws_size,
                              hipStream_t stream)
{
    const float* x    = (const float*)d_in[0];
    const float* hx   = (const float*)d_in[1];
    const float* cx   = (const float*)d_in[2];
    const float* Wih  = (const float*)d_in[3];
    const float* Whh  = (const float*)d_in[4];
    const float* bih  = (const float*)d_in[5];
    const float* bhh  = (const float*)d_in[6];
    const float* Wlin = (const float*)d_in[7];
    const float* blin = (const float*)d_in[8];
    float* out = (float*)d_out;

    half_t* wih_s = (half_t*)d_ws;             // 512 KB
    half_t* whh_s = wih_s + 1024 * 256;        // 512 KB

    shuffle_w_kernel<<<512, 64, 0, stream>>>(Wih, wih_s);
    shuffle_w_kernel<<<512, 64, 0, stream>>>(Whh, whh_s);
    lstm_kernel<<<200, 512, 0, stream>>>(x, hx, cx, bih, bhh, Wlin, blin,
                                         wih_s, whh_s, out);
}

// Round 26
// 222.971 us; speedup vs baseline: 1.1480x; 1.1218x over previous
//
#include <hip/hip_runtime.h>
#include <stdint.h>
#include <stddef.h>

// ---------- types ----------
typedef _Float16 half_t;
typedef half_t half8  __attribute__((ext_vector_type(8)));
typedef half_t half4v __attribute__((ext_vector_type(4)));
typedef float  f32x4  __attribute__((ext_vector_type(4)));

__device__ __forceinline__ float fast_sigmoid(float x) {
    float e = __builtin_amdgcn_exp2f(-1.44269504f * x);
    return __builtin_amdgcn_rcpf(1.0f + e);
}
__device__ __forceinline__ float fast_tanh(float x) {
    float e = __builtin_amdgcn_exp2f(2.88539008f * x);
    return 1.0f - 2.0f * __builtin_amdgcn_rcpf(1.0f + e);
}

// ---------------------------------------------------------------------------
// Prep: W [1024][256] f32 row-major -> wave-window-contiguous MFMA-B order.
// Tile T = g*16 + w*2 + j; slot v = g*2 + j. Element addr:
// (((w*8 + kt)*8 + v)*64 + l)*8 + e  -- window kt's 8 fragments for wave w
// are one contiguous 8 KB run (two 4 KB halves: v 0..3, v 4..7).
// Value: B[k = kt*32 + (l>>4)*8 + e, col = T*16 + (l&15)] -- same bijection
// as the LDS A-fragments (validated R1-R25, absmax 2e-3).
// ---------------------------------------------------------------------------
__global__ __launch_bounds__(64) void shuffle_w_kernel(
    const float* __restrict__ W, half_t* __restrict__ out)
{
    const int blk = blockIdx.x;         // 512 = 64 T * 8 kt
    const int T = blk >> 3, kt = blk & 7;
    const int l = threadIdx.x;
    const int w = (T & 15) >> 1, j = T & 1, g = T >> 4;
    const int v = g * 2 + j;
    const int col = T * 16 + (l & 15);
    const int k0 = kt * 32 + ((l >> 4) << 3);
    half8 vv;
#pragma unroll
    for (int e = 0; e < 8; ++e) vv[e] = (half_t)W[col * 256 + k0 + e];
    *reinterpret_cast<half8*>(
        out + ((size_t)((w * 8 + kt) * 8 + v) * 64 + l) * 8) = vv;
}

// ---------------------------------------------------------------------------
// SINGLE-PASS 4-gate GEMM, half-window B dbuf (R22) + A kt-dbuf (R23).
// kt windows fenced (sched_barrier) -- the R4-R23 proven anti-hoist.
// a(kt+1) prefetched during half-window 1 into ping-pong aP[kt&1]
// (#pragma unroll 2 makes kt parity static -- no dynamic indexing).
// In-flight: bA/bB 32 + aP 32 + bases ~8 (acc in AGPR).
// NOTE (R25 lesson): this kernel sits at the 128-arch-reg cliff; ANY
// instruction-stream perturbation (even s_setprio) re-spills. Do not touch.
// ---------------------------------------------------------------------------
template <typename CoWork>
__device__ __forceinline__ void gemm_all(
    f32x4* acc, const half_t* __restrict__ lhx,
    const half_t* Ws, int w, int lm, int lg, int l, CoWork&& cowork)
{
    asm volatile("" : "+v"(Ws));   // anti-LICM: recompute bases per call
    const half_t* wb = Ws + (size_t)w * 32768 + l * 8;
    half8 bA[4], bB[4];
    half8 aP[2][4];                // ping-pong A fragments, indexed by kt&1
#pragma unroll
    for (int v = 0; v < 4; ++v)
        bA[v] = *reinterpret_cast<const half8*>(wb + v * 512);
#pragma unroll
    for (int mt = 0; mt < 4; ++mt) {
        const int p = mt * 16 + lm;
        const int k = (lg * 8) ^ ((p & 7) << 4);
        aP[0][mt] = *reinterpret_cast<const half8*>(&lhx[p * 256 + k]);
    }

#pragma unroll 2
    for (int kt = 0; kt < 8; ++kt) {
        const half_t* q  = wb + kt * 4096;
        const half_t* qn = wb + ((kt + 1) & 7) * 4096;
        // half 0: prefetch this kt's v=4..7 into bB; MFMA v=0..3 with bA
#pragma unroll
        for (int v = 0; v < 4; ++v)
            bB[v] = *reinterpret_cast<const half8*>(q + 2048 + v * 512);
#pragma unroll
        for (int v = 0; v < 4; ++v)
#pragma unroll
            for (int mt = 0; mt < 4; ++mt)
                acc[mt * 8 + v] = __builtin_amdgcn_mfma_f32_16x16x32_f16(
                    aP[kt & 1][mt], bA[v], acc[mt * 8 + v], 0, 0, 0);
        cowork(kt * 2);
        __builtin_amdgcn_sched_barrier(0);
        // half 1: prefetch next kt's v=0..3 into bA and next kt's a into
        // aP[(kt+1)&1] (kt=7 wraps -- value unused, harmless);
        // MFMA v=4..7 with bB
#pragma unroll
        for (int v = 0; v < 4; ++v)
            bA[v] = *reinterpret_cast<const half8*>(qn + v * 512);
#pragma unroll
        for (int mt = 0; mt < 4; ++mt) {
            const int p = mt * 16 + lm;
            const int k = ((((kt + 1) & 7) * 32) + lg * 8) ^ ((p & 7) << 4);
            aP[(kt + 1) & 1][mt] =
                *reinterpret_cast<const half8*>(&lhx[p * 256 + k]);
        }
#pragma unroll
        for (int v = 0; v < 4; ++v)
#pragma unroll
            for (int mt = 0; mt < 4; ++mt)
                acc[mt * 8 + 4 + v] = __builtin_amdgcn_mfma_f32_16x16x32_f16(
                    aP[kt & 1][mt], bB[v], acc[mt * 8 + 4 + v], 0, 0, 0);
        cowork(kt * 2 + 1);
        __builtin_amdgcn_sched_barrier(0);
    }
}

// ---------------------------------------------------------------------------
// Persistent LSTM: block = 64 rows x 16 steps, 8 waves (512 threads),
// 1 blk/CU, 2 waves/SIMD. R23 configuration -- the session's best
// (223 us, ZERO spills). Structural walls measured shut: 128-arch-reg cap
// (R15/R17/R24/R25 all re-spilled), 2-blocks/CU doubles L2 W-stream
// (R13/R20), trans/barrier lockstep can't be coworked within the cap.
// LDS: hx 32 KB (XOR-swizzled) + xp 128 KB = 160 KB.
// ---------------------------------------------------------------------------
__global__ __launch_bounds__(512)
void lstm_kernel(
    const float* __restrict__ x,      // [8][256][1600]
    const float* __restrict__ hx0,    // [12800][256]
    const float* __restrict__ cx0,    // [12800][256]
    const float* __restrict__ b_ih,   // [1024]
    const float* __restrict__ b_hh,   // [1024]
    const float* __restrict__ W_lin,  // [2][256]
    const float* __restrict__ b_lin,  // [2]
    const half_t* __restrict__ Wih_s, // shuffled f16
    const half_t* __restrict__ Whh_s, // shuffled f16
    float* __restrict__ out)          // [12800][16][2]
{
    __shared__ __align__(16) half_t lds_hx[64 * 256];        // 32 KB
    __shared__ __align__(16) half_t lds_xp[8 * 32 * 64 * 4]; // 128 KB

    const int tid = threadIdx.x;
    const int w  = tid >> 6;   // wave 0..7 owns h-cols [w*32, w*32+32)
    const int l  = tid & 63;
    const int lm = l & 15;
    const int lg = l >> 4;
    const int w2 = w * 2;

    const int row0 = blockIdx.x * 64;     // 200 blocks * 64 rows
    const int bb_  = row0 / 1600;
    const int p0   = row0 % 1600;

    // ---- stage x tile into lds_hx, f16 swizzled (coalesced on p) ----
    {
        const float* xin = x + (size_t)bb_ * 409600 + p0;   // x[b][c][p0+p]
        for (int it = 0; it < 32; ++it) {
            int idx = it * 512 + tid;
            int p = idx & 63, c = idx >> 6;
            lds_hx[p * 256 + (c ^ ((p & 7) << 4))] = (half_t)xin[c * 1600 + p];
        }
    }
    __syncthreads();

    f32x4 acc[32];
    auto nocw = [](int) {};

    // ---------------- phase 0: x_proj = x @ W_ih^T + b_ih + b_hh ----------
#pragma unroll
    for (int g = 0; g < 4; ++g)
#pragma unroll
        for (int j = 0; j < 2; ++j) {
            int col = (g * 16 + w2 + j) * 16 + lm;
            float bias = b_ih[col] + b_hh[col];
#pragma unroll
            for (int mt = 0; mt < 4; ++mt)
                acc[mt * 8 + g * 2 + j] = (f32x4){bias, bias, bias, bias};
        }
    gemm_all(acc, lds_hx, Wih_s, w, lm, lg, l, nocw);

    // dump x_proj to own-wave LDS region as f16 (read back identically)
#pragma unroll
    for (int f = 0; f < 32; ++f) {
        half4v xv;
#pragma unroll
        for (int r = 0; r < 4; ++r) xv[r] = (half_t)acc[f][r];
        *reinterpret_cast<half4v*>(&lds_xp[((w * 32 + f) * 64 + l) * 4]) = xv;
    }
    __syncthreads();   // x tile fully consumed, xp written

    // ---- stage h0 into lds_hx (coalesced on c); cx into registers ----
    {
        const float* hin = hx0 + (size_t)row0 * 256;
        for (int it = 0; it < 32; ++it) {
            int idx = it * 512 + tid;
            int c = idx & 255, p = idx >> 8;
            lds_hx[p * 256 + (c ^ ((p & 7) << 4))] = (half_t)hin[p * 256 + c];
        }
    }
    float cxr[32];
#pragma unroll
    for (int mt = 0; mt < 4; ++mt)
#pragma unroll
        for (int j = 0; j < 2; ++j)
#pragma unroll
            for (int r = 0; r < 4; ++r) {
                int p = mt * 16 + lg * 4 + r;
                int c = w * 32 + j * 16 + lm;
                cxr[(mt * 2 + j) * 4 + r] = cx0[(size_t)(row0 + p) * 256 + c];
            }
    const float blin0 = b_lin[0], blin1 = b_lin[1];
    const int ph = tid >> 3;          // head: row 0..63
    const int ho = (tid >> 2) & 1;    // head: output 0..1
    const int hq = tid & 3;           // head: quarter of 256 h-cols
    __syncthreads();

    // ---------------- 16 recurrent steps ----------------
#pragma unroll 1
    for (int t = 0; t < 16; ++t) {
        // head(t-1): one cb per half-window (16 total); W_lin float4
        // pipelined one half-window ahead (8-reg state)
        const float* wl = W_lin + ho * 256 + hq * 64;
        asm volatile("" : "+v"(wl));
        float hs = 0.0f;
        float4 hwv;
        if (t > 0) hwv = *reinterpret_cast<const float4*>(wl);
        auto head_cw = [&](int wi) {
            if (t > 0) {
                int c0 = hq * 64 + wi * 4;
                half4v u = *reinterpret_cast<const half4v*>(
                    &lds_hx[ph * 256 + (c0 ^ ((ph & 7) << 4))]);
                float4 wv = hwv;
                if (wi < 15)
                    hwv = *reinterpret_cast<const float4*>(wl + (wi + 1) * 4);
                float h0 = (float)u[0], h1 = (float)u[1];
                float h2 = (float)u[2], h3 = (float)u[3];
                hs += fmaxf(h0, 0.01f * h0) * wv.x;
                hs += fmaxf(h1, 0.01f * h1) * wv.y;
                hs += fmaxf(h2, 0.01f * h2) * wv.z;
                hs += fmaxf(h3, 0.01f * h3) * wv.w;
            }
        };

        // acc init = x_proj, software-pipelined chunks (loads of chunk c+1
        // issue before chunk c's cvts; full unroll -> static indices)
        {
            half4v ib[2][4];
#pragma unroll
            for (int f = 0; f < 4; ++f)
                ib[0][f] = *reinterpret_cast<const half4v*>(
                    &lds_xp[((w * 32 + f) * 64 + l) * 4]);
#pragma unroll
            for (int c = 0; c < 8; ++c) {
                if (c < 7) {
#pragma unroll
                    for (int f = 0; f < 4; ++f)
                        ib[(c + 1) & 1][f] = *reinterpret_cast<const half4v*>(
                            &lds_xp[((w * 32 + (c + 1) * 4 + f) * 64 + l) * 4]);
                }
#pragma unroll
                for (int f = 0; f < 4; ++f)
#pragma unroll
                    for (int r = 0; r < 4; ++r)
                        acc[c * 4 + f][r] = (float)ib[c & 1][f][r];
                __builtin_amdgcn_sched_barrier(0);
            }
        }

        // single GEMM pass: all 4 gates; head(t-1) in the MFMA shadow
        gemm_all(acc, lds_hx, Whh_s, w, lm, lg, l, head_cw);
        if (t > 0) {
            hs += __shfl_xor(hs, 1);
            hs += __shfl_xor(hs, 2);
            if (hq == 0)
                out[((size_t)(row0 + ph) * 16 + (t - 1)) * 2 + ho] =
                    hs + (ho ? blin1 : blin0);
        }

        __syncthreads();   // all waves finished reading lds_hx(t)

        // epilogue: full cell update (all 4 gates local); write hx(t+1)
#pragma unroll
        for (int mt = 0; mt < 4; ++mt)
#pragma unroll
            for (int j = 0; j < 2; ++j)
#pragma unroll
                for (int r = 0; r < 4; ++r) {
                    const int ci = (mt * 2 + j) * 4 + r;
                    float iv = acc[mt * 8 + 0 + j][r];
                    float fv = acc[mt * 8 + 2 + j][r];
                    float gv = acc[mt * 8 + 4 + j][r];
                    float ov = acc[mt * 8 + 6 + j][r];
                    float cxn = fast_sigmoid(fv) * cxr[ci] +
                                fast_sigmoid(iv) * fast_tanh(gv);
                    cxr[ci] = cxn;
                    float h = fast_sigmoid(ov) * fast_tanh(cxn);
                    int p  = mt * 16 + lg * 4 + r;
                    int cc = w * 32 + j * 16 + lm;
                    lds_hx[p * 256 + (cc ^ ((p & 7) << 4))] = (half_t)h;
                }
        __syncthreads();   // hx(t+1) visible to all (next gemm + head)
    }

    // ---- final head (t = 15) ----
    {
        const float* wl = W_lin + ho * 256 + hq * 64;
        asm volatile("" : "+v"(wl));
        float s = 0.0f;
#pragma unroll 2
        for (int cb = 0; cb < 16; ++cb) {
            int c0 = hq * 64 + cb * 4;
            half4v u = *reinterpret_cast<const half4v*>(
                &lds_hx[ph * 256 + (c0 ^ ((ph & 7) << 4))]);
            float4 wv = *reinterpret_cast<const float4*>(wl + cb * 4);
            float h0 = (float)u[0], h1 = (float)u[1];
            float h2 = (float)u[2], h3 = (float)u[3];
            s += fmaxf(h0, 0.01f * h0) * wv.x;
            s += fmaxf(h1, 0.01f * h1) * wv.y;
            s += fmaxf(h2, 0.01f * h2) * wv.z;
            s += fmaxf(h3, 0.01f * h3) * wv.w;
        }
        s += __shfl_xor(s, 1);
        s += __shfl_xor(s, 2);
        if (hq == 0)
            out[((size_t)(row0 + ph) * 16 + 15) * 2 + ho] =
                s + (ho ? blin1 : blin0);
    }
}

// ---------------------------------------------------------------------------
extern "C" void kernel_launch(void* const* d_in, const int* in_sizes, int n_in,
                              void* d_out, int out_size, void* d_ws, size_t ws_size,
                              hipStream_t stream)
{
    const float* x    = (const float*)d_in[0];
    const float* hx   = (const float*)d_in[1];
    const float* cx   = (const float*)d_in[2];
    const float* Wih  = (const float*)d_in[3];
    const float* Whh  = (const float*)d_in[4];
    const float* bih  = (const float*)d_in[5];
    const float* bhh  = (const float*)d_in[6];
    const float* Wlin = (const float*)d_in[7];
    const float* blin = (const float*)d_in[8];
    float* out = (float*)d_out;

    half_t* wih_s = (half_t*)d_ws;             // 512 KB
    half_t* whh_s = wih_s + 1024 * 256;        // 512 KB

    shuffle_w_kernel<<<512, 64, 0, stream>>>(Wih, wih_s);
    shuffle_w_kernel<<<512, 64, 0, stream>>>(Whh, whh_s);
    lstm_kernel<<<200, 512, 0, stream>>>(x, hx, cx, bih, bhh, Wlin, blin,
                                         wih_s, whh_s, out);
}